// Round 12
// baseline (137.305 us; speedup 1.0000x reference)
//
#include <hip/hip_runtime.h>

#define LL 8
#define NN 100000
#define HH 128
#define KT 1024
#define BM 64
#define NNHH (NN * HH)

typedef __attribute__((ext_vector_type(4))) float f32x4;
typedef __attribute__((ext_vector_type(8))) short bf16x8;
typedef __attribute__((ext_vector_type(8))) unsigned short u16x8;

__device__ __forceinline__ unsigned short f2bf(float f) {
    unsigned u = __float_as_uint(f);
    unsigned r = ((u >> 16) & 1u) + 0x7fffu;   // RNE
    return (unsigned short)((u + r) >> 16);
}
__device__ __forceinline__ float bf2f(unsigned short s) {
    return __uint_as_float(((unsigned)s) << 16);
}
__device__ __forceinline__ f32x4 ntload4(const float* p) {
    return __builtin_nontemporal_load(reinterpret_cast<const f32x4*>(p));
}

// Pre-pack w_ref (f32 [128 cols][1024 k]) -> bf16 in fragment order:
// wp[(k8*128 + col)*8 + e] = bf16(w_ref[col][k8*8+e]),  k8 = k/8.
__global__ __launch_bounds__(256) void pack_w_kernel(const float* __restrict__ w_ref,
                                                     unsigned short* __restrict__ wp) {
    int gid = blockIdx.x * 256 + threadIdx.x;   // 0..16383
    int col = gid >> 7;
    int k8  = gid & 127;
    const float* s = w_ref + (size_t)col * KT + (size_t)k8 * 8;
    float4 v0 = *reinterpret_cast<const float4*>(s);
    float4 v1 = *reinterpret_cast<const float4*>(s + 4);
    u16x8 p;
    p[0] = f2bf(v0.x); p[1] = f2bf(v0.y); p[2] = f2bf(v0.z); p[3] = f2bf(v0.w);
    p[4] = f2bf(v1.x); p[5] = f2bf(v1.y); p[6] = f2bf(v1.z); p[7] = f2bf(v1.w);
    *reinterpret_cast<u16x8*>(wp + (size_t)(k8 * 128 + col) * 8) = p;
}

// Block = 64 nodes, 512 threads = 8 waves, ONE block/CU (130KB LDS), 256 VGPR
// headroom (__launch_bounds__(512,1)) so the register pipelines survive
// codegen. Wave w: 64 nodes x cols [w*16,+16). Interleaved per-layer pipeline:
// A depth-3 register prefetch (2 rows x 32B/thread/layer), B depth-2, lgkm-only
// barriers (loads stay in flight across s_barrier), 8 layer-resident bf16 LDS
// tiles, sx+softmax+weighted-sum epilogue fed from LDS. xs read from HBM ONCE.
__global__ __launch_bounds__(512, 1)
void gamlp_main(const float* __restrict__ xs,
                const unsigned short* __restrict__ wp,
                const float* __restrict__ b_ref,
                const float* __restrict__ w_att,
                const float* __restrict__ b_att_p,
                const float* __restrict__ alpha_p,
                float* __restrict__ out)
{
    __shared__ unsigned short A_lds[LL][BM * 128];  // 8 x 16KB = 128KB, XOR-swizzled slots
    __shared__ float sjk_lds[BM][8];

    const int tid  = threadIdx.x;
    const int lane = tid & 63;
    const int wave = tid >> 6;      // 0..7
    const int colq = lane & 15;
    const int kq   = lane >> 4;
    const int n0   = blockIdx.x * BM;

    const float alpha = *alpha_p;
    const float batt  = *b_att_p;

    // ---- staging map: thread covers rows (tid>>4) and (tid>>4)+32, 16B slot tid&15 ----
    const int slot = tid & 15;
    const int row0 = tid >> 4;          // 0..31
    const int row1 = row0 + 32;         // 32..63
    const int g0 = min(n0 + row0, NN - 1);
    const int g1 = min(n0 + row1, NN - 1);
    const float* src0 = xs + (size_t)g0 * HH + slot * 8;
    const float* src1 = xs + (size_t)g1 * HH + slot * 8;
    const int doff0 = row0 * 128 + ((slot ^ (row0 & 15)) * 8);
    const int doff1 = row1 * 128 + ((slot ^ (row1 & 15)) * 8);

    // wa_x slice for this thread's k-slot (f32)
    const f32x4 wax0 = *reinterpret_cast<const f32x4*>(w_att + HH + slot * 8);
    const f32x4 wax1 = *reinterpret_cast<const f32x4*>(w_att + HH + slot * 8 + 4);

    // ---- B fragment pointer (packed bf16, L2-resident); wave covers 16 cols ----
    const unsigned short* pB = wp + (size_t)(wave * 16 + colq) * 8;
    const float wr = w_att[wave * 16 + colq];
    const float br = b_ref[wave * 16 + colq];

    f32x4 acc[4];
    #pragma unroll
    for (int m = 0; m < 4; m++) acc[m] = (f32x4){0, 0, 0, 0};

    f32x4 pf[3][4];
    bf16x8 BA[4], BB[4], BC[4];

#define ISSUE_B(DST, STEP) do {                                                  \
    const int k8_ = (STEP) * 16;                                                 \
    _Pragma("unroll")                                                            \
    for (int c_ = 0; c_ < 4; c_++)                                               \
        DST[c_] = *reinterpret_cast<const bf16x8*>(                              \
            pB + (size_t)(k8_ + c_ * 4 + kq) * 1024);                            \
} while (0)

#define LOADS(SET, LAY) do {                                                     \
    const size_t g_ = (size_t)(LAY) * NNHH;                                      \
    pf[SET][0] = ntload4(src0 + g_);                                             \
    pf[SET][1] = ntload4(src0 + g_ + 4);                                         \
    pf[SET][2] = ntload4(src1 + g_);                                             \
    pf[SET][3] = ntload4(src1 + g_ + 4);                                         \
} while (0)

// pure convert + LDS write (sx lives in the epilogue)
#define CONVERT_WRITE(SET, LAY) do {                                             \
    u16x8 pk0_, pk1_;                                                            \
    _Pragma("unroll")                                                            \
    for (int e_ = 0; e_ < 4; e_++) {                                             \
        pk0_[e_]   = f2bf(pf[SET][0][e_]);                                       \
        pk0_[e_+4] = f2bf(pf[SET][1][e_]);                                       \
        pk1_[e_]   = f2bf(pf[SET][2][e_]);                                       \
        pk1_[e_+4] = f2bf(pf[SET][3][e_]);                                       \
    }                                                                            \
    *reinterpret_cast<u16x8*>(&A_lds[LAY][doff0]) = pk0_;                        \
    *reinterpret_cast<u16x8*>(&A_lds[LAY][doff1]) = pk1_;                        \
} while (0)

#define LGKM_BARRIER() do {                                                      \
    asm volatile("s_waitcnt lgkmcnt(0)" ::: "memory");                           \
    __builtin_amdgcn_s_barrier();                                                \
} while (0)

    // ---- prologue: B(0),B(1) first; 3 A-layers in flight; convert layer 0 ----
    ISSUE_B(BA, 0);
    ISSUE_B(BB, 1);
    LOADS(0, 0);
    LOADS(1, 1);
    LOADS(2, 2);
    CONVERT_WRITE(0, 0);
    LGKM_BARRIER();

    // ---- main loop: 8 steps (step == layer), fully unrolled ----
    #pragma unroll
    for (int s = 0; s < 8; s++) {
        // (0) B prefetch (depth 2), decoupled from the A HBM stream
        if (s + 2 < 8) ISSUE_B(BC, s + 2);
        // (1) A loads: depth-3 register pipeline
        if (s + 3 < 8) LOADS((s + 3) % 3, s + 3);
        // (2) convert + ds_write next layer
        if (s + 1 < 8) CONVERT_WRITE((s + 1) % 3, s + 1);
        // (3) MFMA on layer s's resident tile with BA = B(s)
        #pragma unroll
        for (int c = 0; c < 4; c++) {
            bf16x8 af[4];
            #pragma unroll
            for (int m = 0; m < 4; m++) {
                int r = m * 16 + colq;
                af[m] = *reinterpret_cast<const bf16x8*>(
                    &A_lds[s][r * 128 + (((c * 4 + kq) ^ colq) * 8)]);
            }
            #pragma unroll
            for (int m = 0; m < 4; m++)
                acc[m] = __builtin_amdgcn_mfma_f32_16x16x32_bf16(af[m], BA[c], acc[m], 0, 0, 0);
        }
        // (4) shift B pipeline
        #pragma unroll
        for (int c = 0; c < 4; c++) { BA[c] = BB[c]; BB[c] = BC[c]; }
        LGKM_BARRIER();
    }

    // ---- sjk: sum over this wave's 16 cols of prelu(jk + b_ref) * wa_ref ----
    // D layout: col = wave*16 + colq, node = m*16 + kq*4 + r
    #pragma unroll
    for (int m = 0; m < 4; m++) {
        float sr[4];
        #pragma unroll
        for (int r = 0; r < 4; r++) {
            float v = acc[m][r] + br;
            v = (v >= 0.f) ? v : alpha * v;
            float sv = v * wr;
            sv += __shfl_xor(sv, 1);
            sv += __shfl_xor(sv, 2);
            sv += __shfl_xor(sv, 4);
            sv += __shfl_xor(sv, 8);
            sr[r] = sv;
        }
        if (colq == 0) {
            #pragma unroll
            for (int r = 0; r < 4; r++)
                sjk_lds[m * 16 + kq * 4 + r][wave] = sr[r];
        }
    }
    __syncthreads();

    // ---- epilogue: sx from LDS bf16 tiles (batched butterfly over 16 values),
    //      softmax, weighted sum. Thread handles nodes row0 and row1. ----
    {
        // pass 1: per-layer partial dots for both nodes (16 independent values)
        float sx0[LL], sx1[LL];
        #pragma unroll
        for (int l = 0; l < LL; l++) {
            u16x8 v0 = *reinterpret_cast<const u16x8*>(&A_lds[l][doff0]);
            u16x8 v1 = *reinterpret_cast<const u16x8*>(&A_lds[l][doff1]);
            float d0 = 0.f, d1 = 0.f;
            #pragma unroll
            for (int e = 0; e < 4; e++) {
                d0 += bf2f(v0[e]) * wax0[e] + bf2f(v0[e + 4]) * wax1[e];
                d1 += bf2f(v1[e]) * wax0[e] + bf2f(v1[e + 4]) * wax1[e];
            }
            sx0[l] = d0; sx1[l] = d1;
        }
        // batched butterfly over the 16-slot group: 4 levels x 16 values (ILP 16)
        #pragma unroll
        for (int mser = 1; mser <= 8; mser <<= 1) {
            #pragma unroll
            for (int l = 0; l < LL; l++) {
                sx0[l] += __shfl_xor(sx0[l], mser);
                sx1[l] += __shfl_xor(sx1[l], mser);
            }
        }
        float sjk0 = 0.f, sjk1 = 0.f;
        #pragma unroll
        for (int w8 = 0; w8 < 8; w8++) { sjk0 += sjk_lds[row0][w8]; sjk1 += sjk_lds[row1][w8]; }

        float sc0[LL], sc1[LL], mx0 = 0.f, mx1 = 0.f;
        #pragma unroll
        for (int l = 0; l < LL; l++) {
            float a = fmaxf(sjk0 + sx0[l] + batt, 0.f);
            float b = fmaxf(sjk1 + sx1[l] + batt, 0.f);
            sc0[l] = a; mx0 = fmaxf(mx0, a);
            sc1[l] = b; mx1 = fmaxf(mx1, b);
        }
        float den0 = 0.f, den1 = 0.f;
        #pragma unroll
        for (int l = 0; l < LL; l++) {
            sc0[l] = __expf(sc0[l] - mx0); den0 += sc0[l];
            sc1[l] = __expf(sc1[l] - mx1); den1 += sc1[l];
        }
        float inv0 = 1.f / den0, inv1 = 1.f / den1;
        f32x4 oa0 = (f32x4){0,0,0,0}, ob0 = (f32x4){0,0,0,0};
        f32x4 oa1 = (f32x4){0,0,0,0}, ob1 = (f32x4){0,0,0,0};
        #pragma unroll
        for (int l = 0; l < LL; l++) {
            u16x8 v0 = *reinterpret_cast<const u16x8*>(&A_lds[l][doff0]);
            u16x8 v1 = *reinterpret_cast<const u16x8*>(&A_lds[l][doff1]);
            float w0 = sc0[l] * inv0, w1 = sc1[l] * inv1;
            #pragma unroll
            for (int e = 0; e < 4; e++) {
                oa0[e] += w0 * bf2f(v0[e]);
                ob0[e] += w0 * bf2f(v0[e + 4]);
                oa1[e] += w1 * bf2f(v1[e]);
                ob1[e] += w1 * bf2f(v1[e + 4]);
            }
        }
        float* op0 = out + (size_t)(n0 + row0) * HH + slot * 8;
        __builtin_nontemporal_store(oa0, reinterpret_cast<f32x4*>(op0));
        __builtin_nontemporal_store(ob0, reinterpret_cast<f32x4*>(op0 + 4));
        if (n0 + row1 < NN) {
            float* op1 = out + (size_t)(n0 + row1) * HH + slot * 8;
            __builtin_nontemporal_store(oa1, reinterpret_cast<f32x4*>(op1));
            __builtin_nontemporal_store(ob1, reinterpret_cast<f32x4*>(op1 + 4));
        }
    }
#undef ISSUE_B
#undef LOADS
#undef CONVERT_WRITE
#undef LGKM_BARRIER
}

extern "C" void kernel_launch(void* const* d_in, const int* in_sizes, int n_in,
                              void* d_out, int out_size, void* d_ws, size_t ws_size,
                              hipStream_t stream) {
    const float* xs     = (const float*)d_in[0];
    const float* w_ref  = (const float*)d_in[1];
    const float* b_ref  = (const float*)d_in[2];
    const float* w_att  = (const float*)d_in[3];
    const float* b_att  = (const float*)d_in[4];
    const float* alpha  = (const float*)d_in[5];
    float* out = (float*)d_out;
    unsigned short* wp = (unsigned short*)d_ws;   // 256 KB packed bf16 weights

    pack_w_kernel<<<64, 256, 0, stream>>>(w_ref, wp);
    const int grid = (NN + BM - 1) / BM;          // 1563
    gamlp_main<<<grid, 512, 0, stream>>>(xs, wp, b_ref, w_att, b_att, alpha, out);
}